// Round 9
// baseline (795.609 us; speedup 1.0000x reference)
//
#include <hip/hip_runtime.h>
#include <hip/hip_cooperative_groups.h>
#include <stdint.h>

namespace cg = cooperative_groups;

#define DIM 256
#define NEG_SLOPE 0.01f

#define NBLK 512            // coarse scatter blocks (2 per CU)
#define MAXK 400            // max coarse buckets (N <= 102400)
#define ROWS_PER_BUCKET 256

typedef float    vfloat4 __attribute__((ext_vector_type(4)));
typedef _Float16 vhalf4  __attribute__((ext_vector_type(4)));
typedef _Float16 half8   __attribute__((ext_vector_type(8)));
typedef float    floatx4 __attribute__((ext_vector_type(4)));
typedef unsigned int vuint2 __attribute__((ext_vector_type(2)));

// ---------------- GEMM: h = x @ W^T + b  (fp16 MFMA, fp32 accum, fp16 out) ---------
// One block = 128 rows x ALL 256 cols  ->  x is streamed exactly once (NT).
// W (256KB) staged from L2 every K-step. BK=32.

#define G2M 128
#define G2LD 36   // padded LDS row in fp16 (72B): 16-row frag reads conflict-free

__global__ __launch_bounds__(256) void gemm_xwT_kernel(
        const float* __restrict__ x, const float* __restrict__ W,
        const float* __restrict__ bias, _Float16* __restrict__ h, int M) {
    __shared__ _Float16 Ax[G2M][G2LD];
    __shared__ _Float16 Bw[DIM][G2LD];

    const int tid  = (int)threadIdx.x;
    const int row0 = blockIdx.x * G2M;
    const int w    = tid >> 6;          // wave 0..3 -> rows w*32..+32
    const int lane = tid & 63;
    const int fr = lane & 15;
    const int fq = lane >> 4;
    const int fk = fq * 8;

    const int srow = tid >> 3;          // 0..31 within a 32-row group
    const int sk4  = (tid & 7) * 4;     // f4 index within 32-k

    floatx4 acc[2][16];
#pragma unroll
    for (int m = 0; m < 2; ++m)
#pragma unroll
        for (int n = 0; n < 16; ++n) acc[m][n] = (floatx4){0.f, 0.f, 0.f, 0.f};

    for (int kk = 0; kk < DIM; kk += 32) {
        // stage A: 128 rows x 32 k (fp32 -> fp16), coalesced, NT (single use)
#pragma unroll
        for (int i = 0; i < 4; ++i) {
            int r = i * 32 + srow;
            int grow = row0 + r;
            vfloat4 f = {0.f, 0.f, 0.f, 0.f};
            if (grow < M)
                f = __builtin_nontemporal_load((const vfloat4*)(&x[(size_t)grow * DIM + kk + sk4]));
            vhalf4 hv = {(_Float16)f.x, (_Float16)f.y, (_Float16)f.z, (_Float16)f.w};
            *(vhalf4*)&Ax[r][sk4] = hv;
        }
        // stage B: 256 cols x 32 k (W rows; cached - W is L2-resident)
#pragma unroll
        for (int i = 0; i < 8; ++i) {
            int c = i * 32 + srow;
            vfloat4 f = *(const vfloat4*)(&W[(size_t)c * DIM + kk + sk4]);
            vhalf4 hv = {(_Float16)f.x, (_Float16)f.y, (_Float16)f.z, (_Float16)f.w};
            *(vhalf4*)&Bw[c][sk4] = hv;
        }
        __syncthreads();

        half8 a0 = *(const half8*)&Ax[w * 32 + fr][fk];
        half8 a1 = *(const half8*)&Ax[w * 32 + 16 + fr][fk];
#pragma unroll
        for (int n = 0; n < 16; ++n) {
            half8 bf = *(const half8*)&Bw[n * 16 + fr][fk];
            acc[0][n] = __builtin_amdgcn_mfma_f32_16x16x32_f16(a0, bf, acc[0][n], 0, 0, 0);
            acc[1][n] = __builtin_amdgcn_mfma_f32_16x16x32_f16(a1, bf, acc[1][n], 0, 0, 0);
        }
        __syncthreads();
    }

#pragma unroll
    for (int n = 0; n < 16; ++n) {
        int col = n * 16 + fr;
        float bv = bias[col];
#pragma unroll
        for (int m = 0; m < 2; ++m) {
#pragma unroll
            for (int j = 0; j < 4; ++j) {
                int row = row0 + w * 32 + m * 16 + fq * 4 + j;
                if (row < M)
                    h[(size_t)row * DIM + col] = (_Float16)(acc[m][n][j] + bv);
            }
        }
    }
}

// ---------------- shared helpers ----------------

__device__ inline int wave_incl_scan(int v) {
    const int lane = threadIdx.x & 63;
#pragma unroll
    for (int off = 1; off < 64; off <<= 1) {
        int t = __shfl_up(v, off, 64);
        if (lane >= off) v += t;
    }
    return v;
}

// ---------------- fused cooperative sort (hist -> scans -> coarse -> fine) --------

__global__ __launch_bounds__(256) void sort_coop_kernel(
        const int* __restrict__ rows, const int* __restrict__ cols,
        const float* __restrict__ vals, int* __restrict__ hist2,
        int* __restrict__ total, int* __restrict__ bbase,
        vuint2* __restrict__ coarse, vuint2* __restrict__ sorted,
        int* __restrict__ offs, int E, int K, int N, int chunk) {
    cg::grid_group grid = cg::this_grid();
    __shared__ int lh[MAXK];
    __shared__ int wtot[4];
    const int tid = (int)threadIdx.x;
    const int b = (int)blockIdx.x;
    const int lane = tid & 63, wid = tid >> 6;
    const int beg = b * chunk;
    const int end = min(beg + chunk, E);

    // phase 1: per-chunk bucket histogram
    for (int i = tid; i < K; i += 256) lh[i] = 0;
    __syncthreads();
    for (int i = beg + tid; i < end; i += 256)
        atomicAdd(&lh[__builtin_nontemporal_load(&rows[i]) >> 8], 1);
    __syncthreads();
    for (int i = tid; i < K; i += 256) hist2[i * NBLK + b] = lh[i];
    grid.sync();

    // phase 2: blocks k<K scan their 512-entry row of hist2 (exclusive, in place)
    if (b < K) {
        int* row = &hist2[b * NBLK];
        int v0 = row[tid * 2], v1 = row[tid * 2 + 1];
        int s = v0 + v1;
        int incl = wave_incl_scan(s);
        if (lane == 63) wtot[wid] = incl;
        __syncthreads();
        int woff = 0;
        for (int ww = 0; ww < wid; ++ww) woff += wtot[ww];
        int excl = woff + incl - s;
        row[tid * 2] = excl;
        row[tid * 2 + 1] = excl + v0;
        if (tid == 255) total[b] = woff + incl;
    }
    grid.sync();

    // phase 3: block 0 wave 0 scans bucket totals -> bbase (exclusive)
    if (b == 0 && wid == 0) {
        int run = 0;
        for (int base = 0; base < K; base += 64) {
            int i = base + lane;
            int v = (i < K) ? total[i] : 0;
            int incl = wave_incl_scan(v);
            if (i < K) bbase[i] = run + incl - v;
            run += __shfl(incl, 63, 64);
        }
    }
    grid.sync();

    // phase 4: coarse scatter into per-(block,bucket) contiguous regions
    for (int i = tid; i < K; i += 256) lh[i] = bbase[i] + hist2[i * NBLK + b];
    __syncthreads();
    for (int i = beg + tid; i < end; i += 256) {
        int r = __builtin_nontemporal_load(&rows[i]);
        int c = __builtin_nontemporal_load(&cols[i]);
        float v = __builtin_nontemporal_load(&vals[i]);
        int pos = atomicAdd(&lh[r >> 8], 1);
        vuint2 rec;
        rec.x = ((unsigned)(r & 255) << 18) | (unsigned)c;
        rec.y = __float_as_uint(v);
        coarse[pos] = rec;
    }
    grid.sync();

    // phase 5: blocks k<K counting-sort their bucket; emit offs[]
    if (b < K) {
        const int row0 = b * ROWS_PER_BUCKET;
        const int fbeg = bbase[b];
        const int fend = (b + 1 < K) ? bbase[b + 1] : E;
        if (tid < ROWS_PER_BUCKET) lh[tid] = 0;
        __syncthreads();
        for (int j = fbeg + tid; j < fend; j += 256)
            atomicAdd(&lh[coarse[j].x >> 18], 1);
        __syncthreads();
        int v = lh[tid];
        int incl = wave_incl_scan(v);
        if (lane == 63) wtot[wid] = incl;
        __syncthreads();
        int woff = 0;
        for (int ww = 0; ww < wid; ++ww) woff += wtot[ww];
        int excl = woff + incl - v;
        lh[tid] = fbeg + excl;
        if (row0 + tid < N) offs[row0 + tid] = fbeg + excl;
        __syncthreads();
        for (int j = fbeg + tid; j < fend; j += 256) {
            vuint2 rec = __builtin_nontemporal_load(&coarse[j]);
            int pos = atomicAdd(&lh[rec.x >> 18], 1);
            sorted[pos] = rec;
        }
    }
}

// ---------------- fallback (non-coop) sort kernels ----------------

__global__ __launch_bounds__(256) void hist2_kernel(const int* __restrict__ rows,
        int* __restrict__ hist2, int E, int K, int chunk) {
    __shared__ int lh[MAXK];
    const int tid = (int)threadIdx.x;
    const int b = (int)blockIdx.x;
    for (int i = tid; i < K; i += 256) lh[i] = 0;
    __syncthreads();
    const int beg = b * chunk;
    const int end = min(beg + chunk, E);
    for (int i = beg + tid; i < end; i += 256)
        atomicAdd(&lh[__builtin_nontemporal_load(&rows[i]) >> 8], 1);
    __syncthreads();
    for (int i = tid; i < K; i += 256) hist2[i * NBLK + b] = lh[i];
}

__global__ __launch_bounds__(256) void scanA_kernel(int* __restrict__ hist2,
        int* __restrict__ total, int K) {
    __shared__ int wtot[4];
    const int tid = (int)threadIdx.x;
    const int lane = tid & 63, wid = tid >> 6;
    const int k = (int)blockIdx.x;
    int* row = &hist2[k * NBLK];
    int v0 = row[tid * 2], v1 = row[tid * 2 + 1];
    int s = v0 + v1;
    int incl = wave_incl_scan(s);
    if (lane == 63) wtot[wid] = incl;
    __syncthreads();
    int woff = 0;
    for (int ww = 0; ww < wid; ++ww) woff += wtot[ww];
    int excl = woff + incl - s;
    row[tid * 2] = excl;
    row[tid * 2 + 1] = excl + v0;
    if (tid == 255) total[k] = woff + incl;
}

__global__ __launch_bounds__(64) void scanB_kernel(const int* __restrict__ total,
        int* __restrict__ bbase, int K) {
    const int lane = (int)threadIdx.x;
    int run = 0;
    for (int b = 0; b < K; b += 64) {
        int i = b + lane;
        int v = (i < K) ? total[i] : 0;
        int incl = wave_incl_scan(v);
        if (i < K) bbase[i] = run + incl - v;
        run += __shfl(incl, 63, 64);
    }
}

__global__ __launch_bounds__(256) void coarse_scatter_kernel(
        const int* __restrict__ rows, const int* __restrict__ cols,
        const float* __restrict__ vals, const int* __restrict__ hist2,
        const int* __restrict__ bbase, vuint2* __restrict__ coarse,
        int E, int K, int chunk) {
    __shared__ int cur[MAXK];
    const int tid = (int)threadIdx.x;
    const int b = (int)blockIdx.x;
    for (int i = tid; i < K; i += 256) cur[i] = bbase[i] + hist2[i * NBLK + b];
    __syncthreads();
    const int beg = b * chunk;
    const int end = min(beg + chunk, E);
    for (int i = beg + tid; i < end; i += 256) {
        int r = __builtin_nontemporal_load(&rows[i]);
        int c = __builtin_nontemporal_load(&cols[i]);
        float v = __builtin_nontemporal_load(&vals[i]);
        int pos = atomicAdd(&cur[r >> 8], 1);
        vuint2 rec;
        rec.x = ((unsigned)(r & 255) << 18) | (unsigned)c;
        rec.y = __float_as_uint(v);
        coarse[pos] = rec;
    }
}

__global__ __launch_bounds__(256) void fine_sort_kernel(
        const vuint2* __restrict__ coarse, const int* __restrict__ bbase,
        vuint2* __restrict__ sorted, int* __restrict__ offs,
        int N, int E, int K) {
    __shared__ int lh[ROWS_PER_BUCKET];
    __shared__ int wtot[4];
    const int tid = (int)threadIdx.x;
    const int lane = tid & 63, wid = tid >> 6;
    const int k = (int)blockIdx.x;
    const int row0 = k * ROWS_PER_BUCKET;
    const int beg = bbase[k];
    const int end = (k + 1 < K) ? bbase[k + 1] : E;
    lh[tid] = 0;
    __syncthreads();
    for (int j = beg + tid; j < end; j += 256)
        atomicAdd(&lh[coarse[j].x >> 18], 1);
    __syncthreads();
    int v = lh[tid];
    int incl = wave_incl_scan(v);
    if (lane == 63) wtot[wid] = incl;
    __syncthreads();
    int woff = 0;
    for (int ww = 0; ww < wid; ++ww) woff += wtot[ww];
    int excl = woff + incl - v;
    lh[tid] = beg + excl;
    if (row0 + tid < N) offs[row0 + tid] = beg + excl;
    __syncthreads();
    for (int j = beg + tid; j < end; j += 256) {
        vuint2 rec = __builtin_nontemporal_load(&coarse[j]);
        int pos = atomicAdd(&lh[rec.x >> 18], 1);
        sorted[pos] = rec;
    }
}

// ---------------- aggregation: one wave per node, 4 nodes/block ----------------

__global__ __launch_bounds__(256) void agg_kernel(
        const _Float16* __restrict__ h, const vuint2* __restrict__ sorted,
        const int* __restrict__ offs, float* __restrict__ out, int N, int E) {
    const int node = blockIdx.x * 4 + ((int)threadIdx.x >> 6);
    if (node >= N) return;
    const int lane = (int)threadIdx.x & 63;
    const int beg = offs[node];
    const int end = (node + 1 < N) ? offs[node + 1] : E;

    float4 acc0 = make_float4(0.f, 0.f, 0.f, 0.f);
    float4 acc1 = make_float4(0.f, 0.f, 0.f, 0.f);

    int j = beg;
    for (; j + 7 < end; j += 8) {
        vuint2 cv[8];
        vhalf4 hv[8];
#pragma unroll
        for (int u = 0; u < 8; ++u) cv[u] = __builtin_nontemporal_load(&sorted[j + u]);
#pragma unroll
        for (int u = 0; u < 8; ++u)
            hv[u] = *(const vhalf4*)(&h[(size_t)(cv[u].x & 0x3FFFF) * DIM + lane * 4]);
#pragma unroll
        for (int u = 0; u < 8; ++u) {
            float v = __uint_as_float(cv[u].y);
            float4* a = (u & 1) ? &acc1 : &acc0;
            a->x += v * (float)hv[u].x;
            a->y += v * (float)hv[u].y;
            a->z += v * (float)hv[u].z;
            a->w += v * (float)hv[u].w;
        }
    }
    for (; j < end; ++j) {
        vuint2 cv = __builtin_nontemporal_load(&sorted[j]);
        float v = __uint_as_float(cv.y);
        vhalf4 hv = *(const vhalf4*)(&h[(size_t)(cv.x & 0x3FFFF) * DIM + lane * 4]);
        acc0.x += v * (float)hv.x; acc0.y += v * (float)hv.y;
        acc0.z += v * (float)hv.z; acc0.w += v * (float)hv.w;
    }
    vfloat4 a;
    a.x = acc0.x + acc1.x;
    a.y = acc0.y + acc1.y;
    a.z = acc0.z + acc1.z;
    a.w = acc0.w + acc1.w;
    a.x = (a.x >= 0.f) ? a.x : NEG_SLOPE * a.x;
    a.y = (a.y >= 0.f) ? a.y : NEG_SLOPE * a.y;
    a.z = (a.z >= 0.f) ? a.z : NEG_SLOPE * a.z;
    a.w = (a.w >= 0.f) ? a.w : NEG_SLOPE * a.w;
    __builtin_nontemporal_store(a, (vfloat4*)(&out[(size_t)node * DIM + lane * 4]));
}

// ---------------- fallback: atomic scatter ----------------

__global__ __launch_bounds__(256) void zero_f32_kernel(float* __restrict__ p, long long n) {
    long long i = (long long)blockIdx.x * blockDim.x + threadIdx.x;
    long long stride = (long long)gridDim.x * blockDim.x;
    for (; i < n; i += stride) p[i] = 0.0f;
}

__global__ __launch_bounds__(64) void edge_atomic_kernel(
        const int* __restrict__ rows, const int* __restrict__ cols,
        const float* __restrict__ vals, const _Float16* __restrict__ h,
        float* __restrict__ out, int E) {
    const int e = blockIdx.x;
    if (e >= E) return;
    const int lane = threadIdx.x;
    const int r = rows[e];
    const int c = cols[e];
    const float v = vals[e];
    vhalf4 hv = *(const vhalf4*)(&h[(size_t)c * DIM + lane * 4]);
    float* dst = &out[(size_t)r * DIM + lane * 4];
    atomicAdd(dst + 0, v * (float)hv.x);
    atomicAdd(dst + 1, v * (float)hv.y);
    atomicAdd(dst + 2, v * (float)hv.z);
    atomicAdd(dst + 3, v * (float)hv.w);
}

__global__ __launch_bounds__(256) void leaky_kernel(float* __restrict__ p, long long n) {
    long long i = (long long)blockIdx.x * blockDim.x + threadIdx.x;
    long long stride = (long long)gridDim.x * blockDim.x;
    for (; i < n; i += stride) {
        float v = p[i];
        p[i] = (v >= 0.f) ? v : NEG_SLOPE * v;
    }
}

// ---------------- launch ----------------

extern "C" void kernel_launch(void* const* d_in, const int* in_sizes, int n_in,
                              void* d_out, int out_size, void* d_ws, size_t ws_size,
                              hipStream_t stream) {
    const float* x    = (const float*)d_in[0];
    const int*   erow = (const int*)d_in[1];
    const int*   ecol = (const int*)d_in[2];
    const float* eval_ = (const float*)d_in[3];
    const float* Ww   = (const float*)d_in[4];
    const float* Wb   = (const float*)d_in[5];
    float* out = (float*)d_out;

    const int N = in_sizes[0] / DIM;
    const int E = in_sizes[1];
    const int K = (N + ROWS_PER_BUCKET - 1) / ROWS_PER_BUCKET;
    const int chunk = (E + NBLK - 1) / NBLK;

    // workspace layout
    char* p = (char*)d_ws;
    _Float16* h = (_Float16*)p;                 p += (size_t)N * DIM * sizeof(_Float16);
    int* hist2 = (int*)p;                       p += (size_t)K * NBLK * sizeof(int);
    int* total = (int*)p;                       p += (size_t)((K + 63) & ~63) * sizeof(int);
    int* bbase = (int*)p;                       p += (size_t)((K + 63) & ~63) * sizeof(int);
    int* offs = (int*)p;                        p += (size_t)N * sizeof(int);
    uintptr_t up = ((uintptr_t)p + 15) & ~(uintptr_t)15;
    vuint2* sorted = (vuint2*)up;
    size_t need_full = (size_t)((char*)sorted - (char*)d_ws) + (size_t)E * sizeof(vuint2);
    size_t need_h = (size_t)N * DIM * sizeof(_Float16);
    bool coarse_fits = ((size_t)out_size * sizeof(float)) >= (size_t)E * sizeof(vuint2);

    dim3 ggrid((N + G2M - 1) / G2M);

    if (ws_size >= need_full && K <= MAXK && coarse_fits && N <= (1 << 18)) {
        vuint2* coarse = (vuint2*)d_out;
        // fused cooperative sort; fallback to 5 separate launches if unsupported
        {
            const int* a_rows = erow; const int* a_cols = ecol; const float* a_vals = eval_;
            int* a_h2 = hist2; int* a_tot = total; int* a_bb = bbase;
            vuint2* a_co = coarse; vuint2* a_so = sorted; int* a_off = offs;
            int a_E = E, a_K = K, a_N = N, a_ch = chunk;
            void* args[] = {&a_rows, &a_cols, &a_vals, &a_h2, &a_tot, &a_bb,
                            &a_co, &a_so, &a_off, &a_E, &a_K, &a_N, &a_ch};
            hipError_t ce = hipLaunchCooperativeKernel((void*)sort_coop_kernel,
                                dim3(NBLK), dim3(256), args, 0, stream);
            if (ce != hipSuccess) {
                hist2_kernel<<<NBLK, 256, 0, stream>>>(erow, hist2, E, K, chunk);
                scanA_kernel<<<K, 256, 0, stream>>>(hist2, total, K);
                scanB_kernel<<<1, 64, 0, stream>>>(total, bbase, K);
                coarse_scatter_kernel<<<NBLK, 256, 0, stream>>>(erow, ecol, eval_,
                        hist2, bbase, coarse, E, K, chunk);
                fine_sort_kernel<<<K, 256, 0, stream>>>(coarse, bbase, sorted, offs, N, E, K);
            }
        }
        gemm_xwT_kernel<<<ggrid, 256, 0, stream>>>(x, Ww, Wb, h, N);
        agg_kernel<<<(N + 3) / 4, 256, 0, stream>>>(h, sorted, offs, out, N, E);
    } else if (ws_size >= need_h) {
        gemm_xwT_kernel<<<ggrid, 256, 0, stream>>>(x, Ww, Wb, h, N);
        zero_f32_kernel<<<2048, 256, 0, stream>>>(out, (long long)N * DIM);
        edge_atomic_kernel<<<E, 64, 0, stream>>>(erow, ecol, eval_, h, out, E);
        leaky_kernel<<<2048, 256, 0, stream>>>(out, (long long)N * DIM);
    }
}

// Round 10
// 558.529 us; speedup vs baseline: 1.4245x; 1.4245x over previous
//
#include <hip/hip_runtime.h>
#include <stdint.h>

#define DIM 256
#define NEG_SLOPE 0.01f

#define NBLK 512            // coarse scatter blocks (2 per CU)
#define MAXK 400            // max coarse buckets (N <= 102400)
#define ROWS_PER_BUCKET 256

typedef float    vfloat4 __attribute__((ext_vector_type(4)));
typedef _Float16 vhalf4  __attribute__((ext_vector_type(4)));
typedef _Float16 half8   __attribute__((ext_vector_type(8)));
typedef float    floatx4 __attribute__((ext_vector_type(4)));
typedef unsigned int vuint2 __attribute__((ext_vector_type(2)));

// ---------------- GEMM: h = x @ W^T + b  (fp16 MFMA, fp32 accum, fp16 out) ---------
// One block = 128 rows x ALL 256 cols  ->  x is streamed exactly once (NT).
// W (256KB, L2-resident) staged per K-step. BK=32.

#define G2M 128
#define G2LD 36   // padded LDS row in fp16 (72B)

__global__ __launch_bounds__(256) void gemm_xwT_kernel(
        const float* __restrict__ x, const float* __restrict__ W,
        const float* __restrict__ bias, _Float16* __restrict__ h, int M) {
    __shared__ _Float16 Ax[G2M][G2LD];
    __shared__ _Float16 Bw[DIM][G2LD];

    const int tid  = (int)threadIdx.x;
    const int row0 = blockIdx.x * G2M;
    const int w    = tid >> 6;          // wave 0..3 -> rows w*32..+32
    const int lane = tid & 63;
    const int fr = lane & 15;
    const int fq = lane >> 4;
    const int fk = fq * 8;

    const int srow = tid >> 3;          // 0..31
    const int sk4  = (tid & 7) * 4;     // 0,4,..,28

    floatx4 acc[2][16];
#pragma unroll
    for (int m = 0; m < 2; ++m)
#pragma unroll
        for (int n = 0; n < 16; ++n) acc[m][n] = (floatx4){0.f, 0.f, 0.f, 0.f};

    for (int kk = 0; kk < DIM; kk += 32) {
        // stage A: 128 rows x 32 k (fp32 -> fp16), coalesced, NT (single use)
#pragma unroll
        for (int i = 0; i < 4; ++i) {
            int r = i * 32 + srow;
            int grow = row0 + r;
            vfloat4 f = {0.f, 0.f, 0.f, 0.f};
            if (grow < M)
                f = __builtin_nontemporal_load((const vfloat4*)(&x[(size_t)grow * DIM + kk + sk4]));
            vhalf4 hv = {(_Float16)f.x, (_Float16)f.y, (_Float16)f.z, (_Float16)f.w};
            *(vhalf4*)&Ax[r][sk4] = hv;
        }
        // stage B: 256 cols x 32 k (W rows; L2-cached)
#pragma unroll
        for (int i = 0; i < 8; ++i) {
            int c = i * 32 + srow;
            vfloat4 f = *(const vfloat4*)(&W[(size_t)c * DIM + kk + sk4]);
            vhalf4 hv = {(_Float16)f.x, (_Float16)f.y, (_Float16)f.z, (_Float16)f.w};
            *(vhalf4*)&Bw[c][sk4] = hv;
        }
        __syncthreads();

        half8 a0 = *(const half8*)&Ax[w * 32 + fr][fk];
        half8 a1 = *(const half8*)&Ax[w * 32 + 16 + fr][fk];
#pragma unroll
        for (int n = 0; n < 16; ++n) {
            half8 bf = *(const half8*)&Bw[n * 16 + fr][fk];
            acc[0][n] = __builtin_amdgcn_mfma_f32_16x16x32_f16(a0, bf, acc[0][n], 0, 0, 0);
            acc[1][n] = __builtin_amdgcn_mfma_f32_16x16x32_f16(a1, bf, acc[1][n], 0, 0, 0);
        }
        __syncthreads();
    }

#pragma unroll
    for (int n = 0; n < 16; ++n) {
        int col = n * 16 + fr;
        float bv = bias[col];
#pragma unroll
        for (int m = 0; m < 2; ++m) {
#pragma unroll
            for (int j = 0; j < 4; ++j) {
                int row = row0 + w * 32 + m * 16 + fq * 4 + j;
                if (row < M)
                    h[(size_t)row * DIM + col] = (_Float16)(acc[m][n][j] + bv);
            }
        }
    }
}

// ---------------- shared helpers ----------------

__device__ inline int wave_incl_scan(int v) {
    const int lane = threadIdx.x & 63;
#pragma unroll
    for (int off = 1; off < 64; off <<= 1) {
        int t = __shfl_up(v, off, 64);
        if (lane >= off) v += t;
    }
    return v;
}

// ---------------- sort kernels (5-dispatch pipeline, measured-good) ----------------

__global__ __launch_bounds__(256) void hist2_kernel(const int* __restrict__ rows,
        int* __restrict__ hist2, int E, int K, int chunk) {
    __shared__ int lh[MAXK];
    const int tid = (int)threadIdx.x;
    const int b = (int)blockIdx.x;
    for (int i = tid; i < K; i += 256) lh[i] = 0;
    __syncthreads();
    const int beg = b * chunk;
    const int end = min(beg + chunk, E);
    for (int i = beg + tid; i < end; i += 256)
        atomicAdd(&lh[__builtin_nontemporal_load(&rows[i]) >> 8], 1);
    __syncthreads();
    for (int i = tid; i < K; i += 256) hist2[i * NBLK + b] = lh[i];
}

__global__ __launch_bounds__(256) void scanA_kernel(int* __restrict__ hist2,
        int* __restrict__ total, int K) {
    __shared__ int wtot[4];
    const int tid = (int)threadIdx.x;
    const int lane = tid & 63, wid = tid >> 6;
    const int k = (int)blockIdx.x;
    int* row = &hist2[k * NBLK];
    int v0 = row[tid * 2], v1 = row[tid * 2 + 1];
    int s = v0 + v1;
    int incl = wave_incl_scan(s);
    if (lane == 63) wtot[wid] = incl;
    __syncthreads();
    int woff = 0;
    for (int ww = 0; ww < wid; ++ww) woff += wtot[ww];
    int excl = woff + incl - s;
    row[tid * 2] = excl;
    row[tid * 2 + 1] = excl + v0;
    if (tid == 255) total[k] = woff + incl;
}

__global__ __launch_bounds__(64) void scanB_kernel(const int* __restrict__ total,
        int* __restrict__ bbase, int K) {
    const int lane = (int)threadIdx.x;
    int run = 0;
    for (int b = 0; b < K; b += 64) {
        int i = b + lane;
        int v = (i < K) ? total[i] : 0;
        int incl = wave_incl_scan(v);
        if (i < K) bbase[i] = run + incl - v;
        run += __shfl(incl, 63, 64);
    }
}

__global__ __launch_bounds__(256) void coarse_scatter_kernel(
        const int* __restrict__ rows, const int* __restrict__ cols,
        const float* __restrict__ vals, const int* __restrict__ hist2,
        const int* __restrict__ bbase, vuint2* __restrict__ coarse,
        int E, int K, int chunk) {
    __shared__ int cur[MAXK];
    const int tid = (int)threadIdx.x;
    const int b = (int)blockIdx.x;
    for (int i = tid; i < K; i += 256) cur[i] = bbase[i] + hist2[i * NBLK + b];
    __syncthreads();
    const int beg = b * chunk;
    const int end = min(beg + chunk, E);
    for (int i = beg + tid; i < end; i += 256) {
        int r = __builtin_nontemporal_load(&rows[i]);
        int c = __builtin_nontemporal_load(&cols[i]);
        float v = __builtin_nontemporal_load(&vals[i]);
        int pos = atomicAdd(&cur[r >> 8], 1);
        vuint2 rec;
        rec.x = ((unsigned)(r & 255) << 18) | (unsigned)c;
        rec.y = __float_as_uint(v);
        coarse[pos] = rec;
    }
}

__global__ __launch_bounds__(256) void fine_sort_kernel(
        const vuint2* __restrict__ coarse, const int* __restrict__ bbase,
        vuint2* __restrict__ sorted, int* __restrict__ offs,
        int N, int E, int K) {
    __shared__ int lh[ROWS_PER_BUCKET];
    __shared__ int wtot[4];
    const int tid = (int)threadIdx.x;
    const int lane = tid & 63, wid = tid >> 6;
    const int k = (int)blockIdx.x;
    const int row0 = k * ROWS_PER_BUCKET;
    const int beg = bbase[k];
    const int end = (k + 1 < K) ? bbase[k + 1] : E;
    lh[tid] = 0;
    __syncthreads();
    for (int j = beg + tid; j < end; j += 256)
        atomicAdd(&lh[coarse[j].x >> 18], 1);
    __syncthreads();
    int v = lh[tid];
    int incl = wave_incl_scan(v);
    if (lane == 63) wtot[wid] = incl;
    __syncthreads();
    int woff = 0;
    for (int ww = 0; ww < wid; ++ww) woff += wtot[ww];
    int excl = woff + incl - v;
    lh[tid] = beg + excl;
    if (row0 + tid < N) offs[row0 + tid] = beg + excl;
    __syncthreads();
    for (int j = beg + tid; j < end; j += 256) {
        vuint2 rec = __builtin_nontemporal_load(&coarse[j]);
        int pos = atomicAdd(&lh[rec.x >> 18], 1);
        sorted[pos] = rec;
    }
}

// ---------------- aggregation: one wave per node, 4 nodes/block ----------------

__global__ __launch_bounds__(256) void agg_kernel(
        const _Float16* __restrict__ h, const vuint2* __restrict__ sorted,
        const int* __restrict__ offs, float* __restrict__ out, int N, int E) {
    const int node = blockIdx.x * 4 + ((int)threadIdx.x >> 6);
    if (node >= N) return;
    const int lane = (int)threadIdx.x & 63;
    const int beg = offs[node];
    const int end = (node + 1 < N) ? offs[node + 1] : E;

    float4 acc0 = make_float4(0.f, 0.f, 0.f, 0.f);
    float4 acc1 = make_float4(0.f, 0.f, 0.f, 0.f);

    int j = beg;
    for (; j + 7 < end; j += 8) {
        vuint2 cv[8];
        vhalf4 hv[8];
#pragma unroll
        for (int u = 0; u < 8; ++u) cv[u] = __builtin_nontemporal_load(&sorted[j + u]);
#pragma unroll
        for (int u = 0; u < 8; ++u)
            hv[u] = *(const vhalf4*)(&h[(size_t)(cv[u].x & 0x3FFFF) * DIM + lane * 4]);
#pragma unroll
        for (int u = 0; u < 8; ++u) {
            float v = __uint_as_float(cv[u].y);
            float4* a = (u & 1) ? &acc1 : &acc0;
            a->x += v * (float)hv[u].x;
            a->y += v * (float)hv[u].y;
            a->z += v * (float)hv[u].z;
            a->w += v * (float)hv[u].w;
        }
    }
    for (; j < end; ++j) {
        vuint2 cv = __builtin_nontemporal_load(&sorted[j]);
        float v = __uint_as_float(cv.y);
        vhalf4 hv = *(const vhalf4*)(&h[(size_t)(cv.x & 0x3FFFF) * DIM + lane * 4]);
        acc0.x += v * (float)hv.x; acc0.y += v * (float)hv.y;
        acc0.z += v * (float)hv.z; acc0.w += v * (float)hv.w;
    }
    vfloat4 a;
    a.x = acc0.x + acc1.x;
    a.y = acc0.y + acc1.y;
    a.z = acc0.z + acc1.z;
    a.w = acc0.w + acc1.w;
    a.x = (a.x >= 0.f) ? a.x : NEG_SLOPE * a.x;
    a.y = (a.y >= 0.f) ? a.y : NEG_SLOPE * a.y;
    a.z = (a.z >= 0.f) ? a.z : NEG_SLOPE * a.z;
    a.w = (a.w >= 0.f) ? a.w : NEG_SLOPE * a.w;
    __builtin_nontemporal_store(a, (vfloat4*)(&out[(size_t)node * DIM + lane * 4]));
}

// ---------------- fallback: atomic scatter ----------------

__global__ __launch_bounds__(256) void zero_f32_kernel(float* __restrict__ p, long long n) {
    long long i = (long long)blockIdx.x * blockDim.x + threadIdx.x;
    long long stride = (long long)gridDim.x * blockDim.x;
    for (; i < n; i += stride) p[i] = 0.0f;
}

__global__ __launch_bounds__(64) void edge_atomic_kernel(
        const int* __restrict__ rows, const int* __restrict__ cols,
        const float* __restrict__ vals, const _Float16* __restrict__ h,
        float* __restrict__ out, int E) {
    const int e = blockIdx.x;
    if (e >= E) return;
    const int lane = threadIdx.x;
    const int r = rows[e];
    const int c = cols[e];
    const float v = vals[e];
    vhalf4 hv = *(const vhalf4*)(&h[(size_t)c * DIM + lane * 4]);
    float* dst = &out[(size_t)r * DIM + lane * 4];
    atomicAdd(dst + 0, v * (float)hv.x);
    atomicAdd(dst + 1, v * (float)hv.y);
    atomicAdd(dst + 2, v * (float)hv.z);
    atomicAdd(dst + 3, v * (float)hv.w);
}

__global__ __launch_bounds__(256) void leaky_kernel(float* __restrict__ p, long long n) {
    long long i = (long long)blockIdx.x * blockDim.x + threadIdx.x;
    long long stride = (long long)gridDim.x * blockDim.x;
    for (; i < n; i += stride) {
        float v = p[i];
        p[i] = (v >= 0.f) ? v : NEG_SLOPE * v;
    }
}

// ---------------- launch ----------------

extern "C" void kernel_launch(void* const* d_in, const int* in_sizes, int n_in,
                              void* d_out, int out_size, void* d_ws, size_t ws_size,
                              hipStream_t stream) {
    const float* x    = (const float*)d_in[0];
    const int*   erow = (const int*)d_in[1];
    const int*   ecol = (const int*)d_in[2];
    const float* eval_ = (const float*)d_in[3];
    const float* Ww   = (const float*)d_in[4];
    const float* Wb   = (const float*)d_in[5];
    float* out = (float*)d_out;

    const int N = in_sizes[0] / DIM;
    const int E = in_sizes[1];
    const int K = (N + ROWS_PER_BUCKET - 1) / ROWS_PER_BUCKET;
    const int chunk = (E + NBLK - 1) / NBLK;

    // workspace layout
    char* p = (char*)d_ws;
    _Float16* h = (_Float16*)p;                 p += (size_t)N * DIM * sizeof(_Float16);
    int* hist2 = (int*)p;                       p += (size_t)K * NBLK * sizeof(int);
    int* total = (int*)p;                       p += (size_t)((K + 63) & ~63) * sizeof(int);
    int* bbase = (int*)p;                       p += (size_t)((K + 63) & ~63) * sizeof(int);
    int* offs = (int*)p;                        p += (size_t)N * sizeof(int);
    uintptr_t up = ((uintptr_t)p + 15) & ~(uintptr_t)15;
    vuint2* sorted = (vuint2*)up;
    size_t need_full = (size_t)((char*)sorted - (char*)d_ws) + (size_t)E * sizeof(vuint2);
    size_t need_h = (size_t)N * DIM * sizeof(_Float16);
    bool coarse_fits = ((size_t)out_size * sizeof(float)) >= (size_t)E * sizeof(vuint2);

    dim3 ggrid((N + G2M - 1) / G2M);

    if (ws_size >= need_full && K <= MAXK && coarse_fits && N <= (1 << 18)) {
        vuint2* coarse = (vuint2*)d_out;
        hist2_kernel<<<NBLK, 256, 0, stream>>>(erow, hist2, E, K, chunk);
        scanA_kernel<<<K, 256, 0, stream>>>(hist2, total, K);
        scanB_kernel<<<1, 64, 0, stream>>>(total, bbase, K);
        coarse_scatter_kernel<<<NBLK, 256, 0, stream>>>(erow, ecol, eval_, hist2,
                                                        bbase, coarse, E, K, chunk);
        fine_sort_kernel<<<K, 256, 0, stream>>>(coarse, bbase, sorted, offs, N, E, K);
        gemm_xwT_kernel<<<ggrid, 256, 0, stream>>>(x, Ww, Wb, h, N);
        agg_kernel<<<(N + 3) / 4, 256, 0, stream>>>(h, sorted, offs, out, N, E);
    } else if (ws_size >= need_h) {
        gemm_xwT_kernel<<<ggrid, 256, 0, stream>>>(x, Ww, Wb, h, N);
        zero_f32_kernel<<<2048, 256, 0, stream>>>(out, (long long)N * DIM);
        edge_atomic_kernel<<<E, 64, 0, stream>>>(erow, ecol, eval_, h, out, E);
        leaky_kernel<<<2048, 256, 0, stream>>>(out, (long long)N * DIM);
    }
}

// Round 11
// 420.072 us; speedup vs baseline: 1.8940x; 1.3296x over previous
//
#include <hip/hip_runtime.h>
#include <stdint.h>

#define DIM 256
#define NEG_SLOPE 0.01f

#define NBLK 512            // coarse scatter blocks (2 per CU)
#define MAXK 400            // max coarse buckets (N <= 102400)
#define ROWS_PER_BUCKET 256

typedef float    vfloat4 __attribute__((ext_vector_type(4)));
typedef _Float16 vhalf4  __attribute__((ext_vector_type(4)));
typedef _Float16 half8   __attribute__((ext_vector_type(8)));
typedef float    floatx4 __attribute__((ext_vector_type(4)));
typedef unsigned int vuint2 __attribute__((ext_vector_type(2)));

// ---------------- GEMM: h = x @ W^T + b  (fp16 MFMA, fp32 accum, fp16 out) ---------
// 128x64 tile per 256-thread block (R8 version, measured-good).
// Changes vs R8: x loads are CACHEABLE (not NT) and grid is (col-tiles, row-tiles)
// so the 4 blocks sharing an x panel are dispatch-adjacent -> L2/L3 hits.

#define MBM 128
#define MBN 64
#define MBK 32
#define MLDP 40

__global__ __launch_bounds__(256) void gemm_xwT_kernel(
        const float* __restrict__ x, const float* __restrict__ W,
        const float* __restrict__ bias, _Float16* __restrict__ h, int M) {
    __shared__ _Float16 Ax[MBM][MLDP];
    __shared__ _Float16 Bw[MBN][MLDP];

    const int tid  = (int)threadIdx.x;
    const int row0 = blockIdx.y * MBM;
    const int col0 = blockIdx.x * MBN;
    const int wid  = tid >> 6;
    const int lane = tid & 63;
    const int wr = wid >> 1;
    const int wc = wid & 1;
    const int fr = lane & 15;
    const int fk = (lane >> 4) * 8;

    const int arow = tid >> 1;
    const int ak   = (tid & 1) * 16;
    const int wrow = tid >> 2;
    const int wk   = (tid & 3) * 8;

    floatx4 acc[4][2];
#pragma unroll
    for (int m = 0; m < 4; ++m)
#pragma unroll
        for (int n = 0; n < 2; ++n) acc[m][n] = (floatx4){0.f, 0.f, 0.f, 0.f};

    for (int kk = 0; kk < DIM; kk += MBK) {
        {
            int grow = row0 + arow;
            const float* src = &x[(size_t)grow * DIM + kk + ak];
            half8 h0, h1;
            if (grow < M) {
                vfloat4 f0 = *(const vfloat4*)(src + 0);
                vfloat4 f1 = *(const vfloat4*)(src + 4);
                vfloat4 f2 = *(const vfloat4*)(src + 8);
                vfloat4 f3 = *(const vfloat4*)(src + 12);
                h0 = (half8){(_Float16)f0.x, (_Float16)f0.y, (_Float16)f0.z, (_Float16)f0.w,
                             (_Float16)f1.x, (_Float16)f1.y, (_Float16)f1.z, (_Float16)f1.w};
                h1 = (half8){(_Float16)f2.x, (_Float16)f2.y, (_Float16)f2.z, (_Float16)f2.w,
                             (_Float16)f3.x, (_Float16)f3.y, (_Float16)f3.z, (_Float16)f3.w};
            } else {
                h0 = (half8)(_Float16)0; h1 = (half8)(_Float16)0;
            }
            *(half8*)&Ax[arow][ak]     = h0;
            *(half8*)&Ax[arow][ak + 8] = h1;
        }
        {
            const float* src = &W[(size_t)(col0 + wrow) * DIM + kk + wk];
            vfloat4 f0 = *(const vfloat4*)(src + 0);
            vfloat4 f1 = *(const vfloat4*)(src + 4);
            half8 hb = (half8){(_Float16)f0.x, (_Float16)f0.y, (_Float16)f0.z, (_Float16)f0.w,
                               (_Float16)f1.x, (_Float16)f1.y, (_Float16)f1.z, (_Float16)f1.w};
            *(half8*)&Bw[wrow][wk] = hb;
        }
        __syncthreads();

        half8 a[4], b[2];
#pragma unroll
        for (int m = 0; m < 4; ++m)
            a[m] = *(const half8*)&Ax[wr * 64 + m * 16 + fr][fk];
#pragma unroll
        for (int n = 0; n < 2; ++n)
            b[n] = *(const half8*)&Bw[wc * 32 + n * 16 + fr][fk];
#pragma unroll
        for (int m = 0; m < 4; ++m)
#pragma unroll
            for (int n = 0; n < 2; ++n)
                acc[m][n] = __builtin_amdgcn_mfma_f32_16x16x32_f16(a[m], b[n], acc[m][n], 0, 0, 0);
        __syncthreads();
    }

#pragma unroll
    for (int m = 0; m < 4; ++m) {
#pragma unroll
        for (int n = 0; n < 2; ++n) {
            int col = col0 + wc * 32 + n * 16 + fr;
            float bv = bias[col];
#pragma unroll
            for (int j = 0; j < 4; ++j) {
                int row = row0 + wr * 64 + m * 16 + (lane >> 4) * 4 + j;
                if (row < M)
                    h[(size_t)row * DIM + col] = (_Float16)(acc[m][n][j] + bv);
            }
        }
    }
}

// ---------------- shared helpers ----------------

__device__ inline int wave_incl_scan(int v) {
    const int lane = threadIdx.x & 63;
#pragma unroll
    for (int off = 1; off < 64; off <<= 1) {
        int t = __shfl_up(v, off, 64);
        if (lane >= off) v += t;
    }
    return v;
}

// ---------------- sort kernels (5-dispatch pipeline, measured-good) ----------------

__global__ __launch_bounds__(256) void hist2_kernel(const int* __restrict__ rows,
        int* __restrict__ hist2, int E, int K, int chunk) {
    __shared__ int lh[MAXK];
    const int tid = (int)threadIdx.x;
    const int b = (int)blockIdx.x;
    for (int i = tid; i < K; i += 256) lh[i] = 0;
    __syncthreads();
    const int beg = b * chunk;
    const int end = min(beg + chunk, E);
    for (int i = beg + tid; i < end; i += 256)
        atomicAdd(&lh[__builtin_nontemporal_load(&rows[i]) >> 8], 1);
    __syncthreads();
    for (int i = tid; i < K; i += 256) hist2[i * NBLK + b] = lh[i];
}

__global__ __launch_bounds__(256) void scanA_kernel(int* __restrict__ hist2,
        int* __restrict__ total, int K) {
    __shared__ int wtot[4];
    const int tid = (int)threadIdx.x;
    const int lane = tid & 63, wid = tid >> 6;
    const int k = (int)blockIdx.x;
    int* row = &hist2[k * NBLK];
    int v0 = row[tid * 2], v1 = row[tid * 2 + 1];
    int s = v0 + v1;
    int incl = wave_incl_scan(s);
    if (lane == 63) wtot[wid] = incl;
    __syncthreads();
    int woff = 0;
    for (int ww = 0; ww < wid; ++ww) woff += wtot[ww];
    int excl = woff + incl - s;
    row[tid * 2] = excl;
    row[tid * 2 + 1] = excl + v0;
    if (tid == 255) total[k] = woff + incl;
}

__global__ __launch_bounds__(64) void scanB_kernel(const int* __restrict__ total,
        int* __restrict__ bbase, int K) {
    const int lane = (int)threadIdx.x;
    int run = 0;
    for (int b = 0; b < K; b += 64) {
        int i = b + lane;
        int v = (i < K) ? total[i] : 0;
        int incl = wave_incl_scan(v);
        if (i < K) bbase[i] = run + incl - v;
        run += __shfl(incl, 63, 64);
    }
}

__global__ __launch_bounds__(256) void coarse_scatter_kernel(
        const int* __restrict__ rows, const int* __restrict__ cols,
        const float* __restrict__ vals, const int* __restrict__ hist2,
        const int* __restrict__ bbase, vuint2* __restrict__ coarse,
        int E, int K, int chunk) {
    __shared__ int cur[MAXK];
    const int tid = (int)threadIdx.x;
    const int b = (int)blockIdx.x;
    for (int i = tid; i < K; i += 256) cur[i] = bbase[i] + hist2[i * NBLK + b];
    __syncthreads();
    const int beg = b * chunk;
    const int end = min(beg + chunk, E);
    for (int i = beg + tid; i < end; i += 256) {
        int r = __builtin_nontemporal_load(&rows[i]);
        int c = __builtin_nontemporal_load(&cols[i]);
        float v = __builtin_nontemporal_load(&vals[i]);
        int pos = atomicAdd(&cur[r >> 8], 1);
        vuint2 rec;
        rec.x = ((unsigned)(r & 255) << 18) | (unsigned)c;
        rec.y = __float_as_uint(v);
        coarse[pos] = rec;
    }
}

__global__ __launch_bounds__(256) void fine_sort_kernel(
        const vuint2* __restrict__ coarse, const int* __restrict__ bbase,
        vuint2* __restrict__ sorted, int* __restrict__ offs,
        int N, int E, int K) {
    __shared__ int lh[ROWS_PER_BUCKET];
    __shared__ int wtot[4];
    const int tid = (int)threadIdx.x;
    const int lane = tid & 63, wid = tid >> 6;
    const int k = (int)blockIdx.x;
    const int row0 = k * ROWS_PER_BUCKET;
    const int beg = bbase[k];
    const int end = (k + 1 < K) ? bbase[k + 1] : E;
    lh[tid] = 0;
    __syncthreads();
    for (int j = beg + tid; j < end; j += 256)
        atomicAdd(&lh[coarse[j].x >> 18], 1);
    __syncthreads();
    int v = lh[tid];
    int incl = wave_incl_scan(v);
    if (lane == 63) wtot[wid] = incl;
    __syncthreads();
    int woff = 0;
    for (int ww = 0; ww < wid; ++ww) woff += wtot[ww];
    int excl = woff + incl - v;
    lh[tid] = beg + excl;
    if (row0 + tid < N) offs[row0 + tid] = beg + excl;
    __syncthreads();
    for (int j = beg + tid; j < end; j += 256) {
        vuint2 rec = __builtin_nontemporal_load(&coarse[j]);
        int pos = atomicAdd(&lh[rec.x >> 18], 1);
        sorted[pos] = rec;
    }
}

// ---------------- aggregation: one wave per node, 4 nodes/block ----------------

__global__ __launch_bounds__(256) void agg_kernel(
        const _Float16* __restrict__ h, const vuint2* __restrict__ sorted,
        const int* __restrict__ offs, float* __restrict__ out, int N, int E) {
    const int node = blockIdx.x * 4 + ((int)threadIdx.x >> 6);
    if (node >= N) return;
    const int lane = (int)threadIdx.x & 63;
    const int beg = offs[node];
    const int end = (node + 1 < N) ? offs[node + 1] : E;

    float4 acc0 = make_float4(0.f, 0.f, 0.f, 0.f);
    float4 acc1 = make_float4(0.f, 0.f, 0.f, 0.f);

    int j = beg;
    for (; j + 7 < end; j += 8) {
        vuint2 cv[8];
        vhalf4 hv[8];
#pragma unroll
        for (int u = 0; u < 8; ++u) cv[u] = __builtin_nontemporal_load(&sorted[j + u]);
#pragma unroll
        for (int u = 0; u < 8; ++u)
            hv[u] = *(const vhalf4*)(&h[(size_t)(cv[u].x & 0x3FFFF) * DIM + lane * 4]);
#pragma unroll
        for (int u = 0; u < 8; ++u) {
            float v = __uint_as_float(cv[u].y);
            float4* a = (u & 1) ? &acc1 : &acc0;
            a->x += v * (float)hv[u].x;
            a->y += v * (float)hv[u].y;
            a->z += v * (float)hv[u].z;
            a->w += v * (float)hv[u].w;
        }
    }
    for (; j < end; ++j) {
        vuint2 cv = __builtin_nontemporal_load(&sorted[j]);
        float v = __uint_as_float(cv.y);
        vhalf4 hv = *(const vhalf4*)(&h[(size_t)(cv.x & 0x3FFFF) * DIM + lane * 4]);
        acc0.x += v * (float)hv.x; acc0.y += v * (float)hv.y;
        acc0.z += v * (float)hv.z; acc0.w += v * (float)hv.w;
    }
    vfloat4 a;
    a.x = acc0.x + acc1.x;
    a.y = acc0.y + acc1.y;
    a.z = acc0.z + acc1.z;
    a.w = acc0.w + acc1.w;
    a.x = (a.x >= 0.f) ? a.x : NEG_SLOPE * a.x;
    a.y = (a.y >= 0.f) ? a.y : NEG_SLOPE * a.y;
    a.z = (a.z >= 0.f) ? a.z : NEG_SLOPE * a.z;
    a.w = (a.w >= 0.f) ? a.w : NEG_SLOPE * a.w;
    __builtin_nontemporal_store(a, (vfloat4*)(&out[(size_t)node * DIM + lane * 4]));
}

// ---------------- fallback: atomic scatter ----------------

__global__ __launch_bounds__(256) void zero_f32_kernel(float* __restrict__ p, long long n) {
    long long i = (long long)blockIdx.x * blockDim.x + threadIdx.x;
    long long stride = (long long)gridDim.x * blockDim.x;
    for (; i < n; i += stride) p[i] = 0.0f;
}

__global__ __launch_bounds__(64) void edge_atomic_kernel(
        const int* __restrict__ rows, const int* __restrict__ cols,
        const float* __restrict__ vals, const _Float16* __restrict__ h,
        float* __restrict__ out, int E) {
    const int e = blockIdx.x;
    if (e >= E) return;
    const int lane = threadIdx.x;
    const int r = rows[e];
    const int c = cols[e];
    const float v = vals[e];
    vhalf4 hv = *(const vhalf4*)(&h[(size_t)c * DIM + lane * 4]);
    float* dst = &out[(size_t)r * DIM + lane * 4];
    atomicAdd(dst + 0, v * (float)hv.x);
    atomicAdd(dst + 1, v * (float)hv.y);
    atomicAdd(dst + 2, v * (float)hv.z);
    atomicAdd(dst + 3, v * (float)hv.w);
}

__global__ __launch_bounds__(256) void leaky_kernel(float* __restrict__ p, long long n) {
    long long i = (long long)blockIdx.x * blockDim.x + threadIdx.x;
    long long stride = (long long)gridDim.x * blockDim.x;
    for (; i < n; i += stride) {
        float v = p[i];
        p[i] = (v >= 0.f) ? v : NEG_SLOPE * v;
    }
}

// ---------------- launch ----------------

extern "C" void kernel_launch(void* const* d_in, const int* in_sizes, int n_in,
                              void* d_out, int out_size, void* d_ws, size_t ws_size,
                              hipStream_t stream) {
    const float* x    = (const float*)d_in[0];
    const int*   erow = (const int*)d_in[1];
    const int*   ecol = (const int*)d_in[2];
    const float* eval_ = (const float*)d_in[3];
    const float* Ww   = (const float*)d_in[4];
    const float* Wb   = (const float*)d_in[5];
    float* out = (float*)d_out;

    const int N = in_sizes[0] / DIM;
    const int E = in_sizes[1];
    const int K = (N + ROWS_PER_BUCKET - 1) / ROWS_PER_BUCKET;
    const int chunk = (E + NBLK - 1) / NBLK;

    // workspace layout
    char* p = (char*)d_ws;
    _Float16* h = (_Float16*)p;                 p += (size_t)N * DIM * sizeof(_Float16);
    int* hist2 = (int*)p;                       p += (size_t)K * NBLK * sizeof(int);
    int* total = (int*)p;                       p += (size_t)((K + 63) & ~63) * sizeof(int);
    int* bbase = (int*)p;                       p += (size_t)((K + 63) & ~63) * sizeof(int);
    int* offs = (int*)p;                        p += (size_t)N * sizeof(int);
    uintptr_t up = ((uintptr_t)p + 15) & ~(uintptr_t)15;
    vuint2* sorted = (vuint2*)up;
    size_t need_full = (size_t)((char*)sorted - (char*)d_ws) + (size_t)E * sizeof(vuint2);
    size_t need_h = (size_t)N * DIM * sizeof(_Float16);
    bool coarse_fits = ((size_t)out_size * sizeof(float)) >= (size_t)E * sizeof(vuint2);

    // col-tiles fastest so blocks sharing an x panel are dispatch-adjacent
    dim3 ggrid(DIM / MBN, (N + MBM - 1) / MBM);

    if (ws_size >= need_full && K <= MAXK && coarse_fits && N <= (1 << 18)) {
        vuint2* coarse = (vuint2*)d_out;
        hist2_kernel<<<NBLK, 256, 0, stream>>>(erow, hist2, E, K, chunk);
        scanA_kernel<<<K, 256, 0, stream>>>(hist2, total, K);
        scanB_kernel<<<1, 64, 0, stream>>>(total, bbase, K);
        coarse_scatter_kernel<<<NBLK, 256, 0, stream>>>(erow, ecol, eval_, hist2,
                                                        bbase, coarse, E, K, chunk);
        fine_sort_kernel<<<K, 256, 0, stream>>>(coarse, bbase, sorted, offs, N, E, K);
        gemm_xwT_kernel<<<ggrid, 256, 0, stream>>>(x, Ww, Wb, h, N);
        agg_kernel<<<(N + 3) / 4, 256, 0, stream>>>(h, sorted, offs, out, N, E);
    } else if (ws_size >= need_h) {
        gemm_xwT_kernel<<<ggrid, 256, 0, stream>>>(x, Ww, Wb, h, N);
        zero_f32_kernel<<<2048, 256, 0, stream>>>(out, (long long)N * DIM);
        edge_atomic_kernel<<<E, 64, 0, stream>>>(erow, ecol, eval_, h, out, E);
        leaky_kernel<<<2048, 256, 0, stream>>>(out, (long long)N * DIM);
    }
}